// Round 3
// baseline (9.849 us; speedup 1.0000x reference)
//
#include <hip/hip_runtime.h>
#include <hip/hip_bf16.h>

// TCN: only the last timestep survives. h2[:, :, S-1] needs h1 at S-3..S-1,
// which needs x at S-5..S-1. ~2.4 MFLOP total -> latency bound.
//
// Round 3: 1024 threads/block (16 waves). w2/fw register-prefetched BEFORE
// conv1 so their global-load latency hides under conv1 compute + barrier.
// 8 lanes per conv dot-product, 16 per fc. One block per batch.

#define S_LEN   16384
#define C_IN    64
#define HID     128
#define C_OUT   64
#define KW      3

__global__ __launch_bounds__(1024)
void tcn_tail_kernel(const float* __restrict__ x,
                     const float* __restrict__ w1, const float* __restrict__ b1,
                     const float* __restrict__ w2, const float* __restrict__ b2,
                     const float* __restrict__ fw, const float* __restrict__ fb,
                     float* __restrict__ out)
{
    const int b   = blockIdx.x;
    const int tid = threadIdx.x;

    __shared__ float xf[3][C_IN * KW];  // xf[t][c*3+j] = x[S-5 + t + j][c]
    __shared__ float h1f[HID * KW];     // h1f[h*3+t]   = relu(conv1_h at S-3+t)
    __shared__ float h2s[HID];          // conv2 output at S-1

    // ---- prefetch conv2 weights (12 float4/lane) + fc weights (2 float4/lane)
    //      BEFORE conv1 so latency overlaps conv1 compute ----
    const int h8 = tid >> 3;            // 0..127 (conv group)
    const int q8 = tid & 7;             // lane within 8-group
    const int o16 = tid >> 4;           // 0..63  (fc group)
    const int r16 = tid & 15;

    float4 pw[12];
    {
        const float4* wv = (const float4*)(w2 + (size_t)h8 * (HID * KW));
        #pragma unroll
        for (int m = 0; m < 12; ++m)
            pw[m] = wv[m * 8 + q8];
    }
    float4 pf[2];
    {
        const float4* wv = (const float4*)(fw + (size_t)o16 * HID);
        #pragma unroll
        for (int m = 0; m < 2; ++m)
            pf[m] = wv[m * 16 + r16];
    }

    // ---- stage x tail (320 floats) into 3 flat operand vectors ----
    // x layout (B, S, C): x[b][s][c] -> b*S*C + s*C + c
    const float* xb = x + (size_t)b * S_LEN * C_IN + (size_t)(S_LEN - 5) * C_IN;
    if (tid < 5 * C_IN) {
        const float v = xb[tid];
        const int s = tid >> 6;         // 0..4 (timestep S-5+s)
        const int c = tid & 63;
        #pragma unroll
        for (int t = 0; t < 3; ++t) {
            const int j = s - t;
            if (0 <= j && j < KW) xf[t][c * KW + j] = v;
        }
    }
    __syncthreads();

    // ---- conv1: 128 outputs x 3 timesteps; 8 lanes per output ----
    // h1f[h*3+t] = relu(b1[h] + dot(w1[h,:], xf[t,:]))  (length 192 = 48 chunks)
    {
        const float4* wv = (const float4*)(w1 + (size_t)h8 * (C_IN * KW));
        float a0 = 0.f, a1 = 0.f, a2 = 0.f;
        #pragma unroll
        for (int m = 0; m < 6; ++m) {
            const int ch = m * 8 + q8;
            const float4 w  = wv[ch];
            const float4 p0 = ((const float4*)xf[0])[ch];
            const float4 p1 = ((const float4*)xf[1])[ch];
            const float4 p2 = ((const float4*)xf[2])[ch];
            a0 += w.x * p0.x + w.y * p0.y + w.z * p0.z + w.w * p0.w;
            a1 += w.x * p1.x + w.y * p1.y + w.z * p1.z + w.w * p1.w;
            a2 += w.x * p2.x + w.y * p2.y + w.z * p2.z + w.w * p2.w;
        }
        a0 += __shfl_xor(a0, 1); a0 += __shfl_xor(a0, 2); a0 += __shfl_xor(a0, 4);
        a1 += __shfl_xor(a1, 1); a1 += __shfl_xor(a1, 2); a1 += __shfl_xor(a1, 4);
        a2 += __shfl_xor(a2, 1); a2 += __shfl_xor(a2, 2); a2 += __shfl_xor(a2, 4);
        if (q8 == 0) {
            const float bb = b1[h8];
            h1f[h8 * KW + 0] = fmaxf(a0 + bb, 0.f);
            h1f[h8 * KW + 1] = fmaxf(a1 + bb, 0.f);
            h1f[h8 * KW + 2] = fmaxf(a2 + bb, 0.f);
        }
    }
    __syncthreads();

    // ---- conv2 at S-1: 128 outputs, dot length 384 (96 chunks); 8 lanes/output ----
    // weights already in pw[]
    {
        const float4* hv = (const float4*)h1f;
        float a0 = 0.f, a1 = 0.f, a2 = 0.f, a3 = 0.f;
        #pragma unroll
        for (int m = 0; m < 12; m += 4) {
            const float4 p0 = hv[(m + 0) * 8 + q8];
            const float4 p1 = hv[(m + 1) * 8 + q8];
            const float4 p2 = hv[(m + 2) * 8 + q8];
            const float4 p3 = hv[(m + 3) * 8 + q8];
            const float4 w0 = pw[m + 0], w1v = pw[m + 1];
            const float4 w2v = pw[m + 2], w3v = pw[m + 3];
            a0 += w0.x * p0.x + w0.y * p0.y + w0.z * p0.z + w0.w * p0.w;
            a1 += w1v.x * p1.x + w1v.y * p1.y + w1v.z * p1.z + w1v.w * p1.w;
            a2 += w2v.x * p2.x + w2v.y * p2.y + w2v.z * p2.z + w2v.w * p2.w;
            a3 += w3v.x * p3.x + w3v.y * p3.y + w3v.z * p3.z + w3v.w * p3.w;
        }
        float a = (a0 + a1) + (a2 + a3);
        a += __shfl_xor(a, 1); a += __shfl_xor(a, 2); a += __shfl_xor(a, 4);
        if (q8 == 0) h2s[h8] = fmaxf(a + b2[h8], 0.f);
    }
    __syncthreads();

    // ---- fc: 64 outputs, dot length 128 (32 chunks); 16 lanes per output ----
    // weights already in pf[]
    {
        const float4* hv = (const float4*)h2s;
        const float4 p0 = hv[0 * 16 + r16];
        const float4 p1 = hv[1 * 16 + r16];
        float a = pf[0].x * p0.x + pf[0].y * p0.y + pf[0].z * p0.z + pf[0].w * p0.w
                + pf[1].x * p1.x + pf[1].y * p1.y + pf[1].z * p1.z + pf[1].w * p1.w;
        a += __shfl_xor(a, 1); a += __shfl_xor(a, 2);
        a += __shfl_xor(a, 4); a += __shfl_xor(a, 8);
        if (r16 == 0) out[(size_t)b * C_OUT + o16] = a + fb[o16];
    }
}

extern "C" void kernel_launch(void* const* d_in, const int* in_sizes, int n_in,
                              void* d_out, int out_size, void* d_ws, size_t ws_size,
                              hipStream_t stream) {
    const float* x  = (const float*)d_in[0];
    const float* w1 = (const float*)d_in[1];
    const float* b1 = (const float*)d_in[2];
    const float* w2 = (const float*)d_in[3];
    const float* b2 = (const float*)d_in[4];
    const float* fw = (const float*)d_in[5];
    const float* fb = (const float*)d_in[6];
    float* out = (float*)d_out;

    tcn_tail_kernel<<<16, 1024, 0, stream>>>(x, w1, b1, w2, b2, fw, fb, out);
}

// Round 4
// 9.358 us; speedup vs baseline: 1.0525x; 1.0525x over previous
//
#include <hip/hip_runtime.h>
#include <hip/hip_bf16.h>

// TCN: only the last timestep survives. h2[:, :, S-1] needs h1 at S-3..S-1,
// which needs x at S-5..S-1. ~2.4 MFLOP total -> latency bound.
//
// Final config (best measured, Round 2): 512 threads/block (8 waves), 4 lanes
// per conv dot-product, 8 lanes per fc dot-product, interleaved float4 chunks
// (coalesced 64B weight lines, distinct LDS banks), shfl_xor reductions.
// One block per batch. dur_us ~9.3 us == graph-dispatch floor; kernel body
// itself is ~1 us (reads ~350 KB L2-resident weights + 320-float x tail).

#define S_LEN   16384
#define C_IN    64
#define HID     128
#define C_OUT   64
#define KW      3

__global__ __launch_bounds__(512)
void tcn_tail_kernel(const float* __restrict__ x,
                     const float* __restrict__ w1, const float* __restrict__ b1,
                     const float* __restrict__ w2, const float* __restrict__ b2,
                     const float* __restrict__ fw, const float* __restrict__ fb,
                     float* __restrict__ out)
{
    const int b   = blockIdx.x;
    const int tid = threadIdx.x;

    __shared__ float xf[3][C_IN * KW];  // xf[t][c*3+j] = x[S-5 + t + j][c]
    __shared__ float h1f[HID * KW];     // h1f[h*3+t]   = relu(conv1_h at S-3+t)
    __shared__ float h2s[HID];          // conv2 output at S-1

    // ---- stage x tail (320 floats) directly into the 3 flat operand vectors ----
    // x layout (B, S, C): x[b][s][c] -> b*S*C + s*C + c
    const float* xb = x + (size_t)b * S_LEN * C_IN + (size_t)(S_LEN - 5) * C_IN;
    if (tid < 5 * C_IN) {
        const float v = xb[tid];
        const int s = tid >> 6;       // 0..4  (timestep S-5+s)
        const int c = tid & 63;
        #pragma unroll
        for (int t = 0; t < 3; ++t) {
            const int j = s - t;
            if (0 <= j && j < KW) xf[t][c * KW + j] = v;
        }
    }
    __syncthreads();

    // ---- conv1: 128 outputs x 3 timesteps; 4 lanes per output ----
    // h1f[h*3+t] = relu(b1[h] + dot(w1[h,:], xf[t,:]))   (length 192)
    {
        const int h = tid >> 2;       // 0..127
        const int q = tid & 3;        // lane-within-group
        const float4* wv = (const float4*)(w1 + (size_t)h * (C_IN * KW));
        float a0 = 0.f, a1 = 0.f, a2 = 0.f;
        #pragma unroll
        for (int m = 0; m < 12; ++m) {
            const int ch = m * 4 + q;           // interleaved float4 chunk
            const float4 w  = wv[ch];
            const float4 p0 = ((const float4*)xf[0])[ch];
            const float4 p1 = ((const float4*)xf[1])[ch];
            const float4 p2 = ((const float4*)xf[2])[ch];
            a0 += w.x * p0.x + w.y * p0.y + w.z * p0.z + w.w * p0.w;
            a1 += w.x * p1.x + w.y * p1.y + w.z * p1.z + w.w * p1.w;
            a2 += w.x * p2.x + w.y * p2.y + w.z * p2.z + w.w * p2.w;
        }
        a0 += __shfl_xor(a0, 1); a0 += __shfl_xor(a0, 2);
        a1 += __shfl_xor(a1, 1); a1 += __shfl_xor(a1, 2);
        a2 += __shfl_xor(a2, 1); a2 += __shfl_xor(a2, 2);
        if (q == 0) {
            const float bb = b1[h];
            h1f[h * KW + 0] = fmaxf(a0 + bb, 0.f);
            h1f[h * KW + 1] = fmaxf(a1 + bb, 0.f);
            h1f[h * KW + 2] = fmaxf(a2 + bb, 0.f);
        }
    }
    __syncthreads();

    // ---- conv2 at S-1: 128 outputs, dot length 384; 4 lanes per output ----
    // h2[h] = relu(b2[h] + dot(w2[h,:], h1f[:]))
    {
        const int h = tid >> 2;
        const int q = tid & 3;
        const float4* wv = (const float4*)(w2 + (size_t)h * (HID * KW));
        const float4* hv = (const float4*)h1f;
        float a0 = 0.f, a1 = 0.f, a2 = 0.f, a3 = 0.f;
        #pragma unroll
        for (int m = 0; m < 24; m += 4) {
            const int c0 = (m + 0) * 4 + q;
            const int c1 = (m + 1) * 4 + q;
            const int c2 = (m + 2) * 4 + q;
            const int c3 = (m + 3) * 4 + q;
            const float4 w0 = wv[c0], w1v = wv[c1], w2v = wv[c2], w3v = wv[c3];
            const float4 p0 = hv[c0], p1 = hv[c1], p2 = hv[c2], p3 = hv[c3];
            a0 += w0.x * p0.x + w0.y * p0.y + w0.z * p0.z + w0.w * p0.w;
            a1 += w1v.x * p1.x + w1v.y * p1.y + w1v.z * p1.z + w1v.w * p1.w;
            a2 += w2v.x * p2.x + w2v.y * p2.y + w2v.z * p2.z + w2v.w * p2.w;
            a3 += w3v.x * p3.x + w3v.y * p3.y + w3v.z * p3.z + w3v.w * p3.w;
        }
        float a = (a0 + a1) + (a2 + a3);
        a += __shfl_xor(a, 1); a += __shfl_xor(a, 2);
        if (q == 0) h2s[h] = fmaxf(a + b2[h], 0.f);
    }
    __syncthreads();

    // ---- fc: 64 outputs, dot length 128; 8 lanes per output ----
    {
        const int o = tid >> 3;       // 0..63
        const int r = tid & 7;
        const float4* wv = (const float4*)(fw + (size_t)o * HID);
        const float4* hv = (const float4*)h2s;
        float a = 0.f;
        #pragma unroll
        for (int m = 0; m < 4; ++m) {
            const int ch = m * 8 + r;
            const float4 w  = wv[ch];
            const float4 p  = hv[ch];
            a += w.x * p.x + w.y * p.y + w.z * p.z + w.w * p.w;
        }
        a += __shfl_xor(a, 1); a += __shfl_xor(a, 2); a += __shfl_xor(a, 4);
        if (r == 0) out[(size_t)b * C_OUT + o] = a + fb[o];
    }
}

extern "C" void kernel_launch(void* const* d_in, const int* in_sizes, int n_in,
                              void* d_out, int out_size, void* d_ws, size_t ws_size,
                              hipStream_t stream) {
    const float* x  = (const float*)d_in[0];
    const float* w1 = (const float*)d_in[1];
    const float* b1 = (const float*)d_in[2];
    const float* w2 = (const float*)d_in[3];
    const float* b2 = (const float*)d_in[4];
    const float* fw = (const float*)d_in[5];
    const float* fb = (const float*)d_in[6];
    float* out = (float*)d_out;

    tcn_tail_kernel<<<16, 512, 0, stream>>>(x, w1, b1, w2, b2, fw, fb, out);
}